// Round 8
// baseline (6320.961 us; speedup 1.0000x reference)
//
#include <hip/hip_runtime.h>
#include <hip/hip_bf16.h>
#include <hip/hip_fp16.h>

typedef __attribute__((ext_vector_type(8))) _Float16 f16x8;
typedef __attribute__((ext_vector_type(4))) float f32x4;
typedef __attribute__((ext_vector_type(4))) unsigned int u32x4;

#define NSTEP 511

__device__ __forceinline__ unsigned short f2h(float f){ return __half_as_ushort(__float2half(f)); }
__device__ __forceinline__ float sigf(float z){ return 1.0f/(1.0f + __expf(-z)); }

// 8B coherent publish (L1/L2-bypass; memory-side L3 is the coherent point).
__device__ __forceinline__ void st64_coh(unsigned* p, unsigned lo, unsigned hi){
  unsigned long long v = ((unsigned long long)hi << 32) | (unsigned long long)lo;
  asm volatile("global_store_dwordx2 %0, %1, off sc0 sc1" :: "v"(p), "v"(v) : "memory");
}
// 16x16B coherent loads (lane's 8 fragments x 8 u32) + in-block waitcnt.
__device__ __forceinline__ void ldA16_coh(const unsigned* p, u32x4 r[16]){
  asm volatile(
    "global_load_dwordx4 %0, %16, off sc0 sc1\n\t"
    "global_load_dwordx4 %1, %16, off offset:16 sc0 sc1\n\t"
    "global_load_dwordx4 %2, %16, off offset:128 sc0 sc1\n\t"
    "global_load_dwordx4 %3, %16, off offset:144 sc0 sc1\n\t"
    "global_load_dwordx4 %4, %16, off offset:256 sc0 sc1\n\t"
    "global_load_dwordx4 %5, %16, off offset:272 sc0 sc1\n\t"
    "global_load_dwordx4 %6, %16, off offset:384 sc0 sc1\n\t"
    "global_load_dwordx4 %7, %16, off offset:400 sc0 sc1\n\t"
    "global_load_dwordx4 %8, %16, off offset:512 sc0 sc1\n\t"
    "global_load_dwordx4 %9, %16, off offset:528 sc0 sc1\n\t"
    "global_load_dwordx4 %10, %16, off offset:640 sc0 sc1\n\t"
    "global_load_dwordx4 %11, %16, off offset:656 sc0 sc1\n\t"
    "global_load_dwordx4 %12, %16, off offset:768 sc0 sc1\n\t"
    "global_load_dwordx4 %13, %16, off offset:784 sc0 sc1\n\t"
    "global_load_dwordx4 %14, %16, off offset:896 sc0 sc1\n\t"
    "global_load_dwordx4 %15, %16, off offset:912 sc0 sc1\n\t"
    "s_waitcnt vmcnt(0)"
    : "=v"(r[0]),"=v"(r[1]),"=v"(r[2]),"=v"(r[3]),
      "=v"(r[4]),"=v"(r[5]),"=v"(r[6]),"=v"(r[7]),
      "=v"(r[8]),"=v"(r[9]),"=v"(r[10]),"=v"(r[11]),
      "=v"(r[12]),"=v"(r[13]),"=v"(r[14]),"=v"(r[15])
    : "v"(p) : "memory");
}

// ---- gate tables: T[v][h] = sum_e emb[v,e]*w[e,h] + b[h], v in 0..2 ----
__global__ void k_tables(const float* __restrict__ emb, const float* __restrict__ w,
                         const float* __restrict__ bias, float* __restrict__ T){
  int h = blockIdx.x*256 + threadIdx.x;
  float a0=0.f, a1=0.f, a2=0.f;
  for(int e=0;e<512;e++){
    float we = w[e*1024 + h];
    a0 += emb[e]*we; a1 += emb[512+e]*we; a2 += emb[1024+e]*we;
  }
  float b = bias[h];
  T[h] = a0+b; T[1024+h] = a1+b; T[2048+h] = a2+b;
}

// ---- transpose 1024x1024 f32 -> f16 wT[n][k] = w[k][n] ----
__global__ void k_transpose(const float* __restrict__ w, unsigned short* __restrict__ wT){
  __shared__ float tile[64][65];
  int tr = blockIdx.x & 15, tc = blockIdx.x >> 4;
  int col = threadIdx.x & 63;
  int r0  = threadIdx.x >> 6;
  for(int rr=0; rr<16; rr++){
    int row = rr*4 + r0;
    tile[row][col] = w[(tr*64+row)*1024 + tc*64 + col];
  }
  __syncthreads();
  for(int rr=0; rr<16; rr++){
    int row = rr*4 + r0;
    wT[(tc*64+row)*1024 + tr*64 + col] = f2h(tile[col][row]);
  }
}

// ---- sequential recurrence: 256 WGs = 8 batch-groups x 32 col-slices ----
// c element = u32 { tag=(step+1) << 16 | f16(c) }: tag+data atomic in one
// dword, the A-load IS the sync (poll until all 64 high-halves == t).
// Two planes (read t&1 / write (t+1)&1); init memset(0): plane0 tag0 = c0
// data for t=0; plane1 tag0 != expected 1 -> blocks. One barrier per step.
// Wave wid = q*2 + mh: k-quarter q, 16-row half mh (r5 geometry, VGPR-safe).
__global__ void __launch_bounds__(512,1) k_recur(
    const int* __restrict__ x,
    const unsigned short* __restrict__ wTi,   // w_ih^T f16 [n][k]
    const unsigned short* __restrict__ wTf,
    const unsigned short* __restrict__ wTo,
    const float* __restrict__ Ti, const float* __restrict__ Tf,
    const float* __restrict__ To, const float* __restrict__ Tc,
    unsigned* __restrict__ cpl,               // [2][256][1024] u32 tagged planes
    float* __restrict__ hbuf)
{
  __shared__ __align__(16) float xch[8192];   // 32KB accumulator exchange
  __shared__ __align__(16) float xo[4096];    // 16KB o-gate (last step only)

  const int tid  = threadIdx.x;
  const int wid  = tid >> 6;
  const int lane = tid & 63;
  const int mg   = blockIdx.x & 7;
  const int ng   = blockIdx.x >> 3;
  const int mbase = mg*32;
  const int nbase = ng*32;

  const int mh_w = wid & 1;
  const int q_w  = wid >> 1;

  // ---- B (i,f gates; both 16-col halves; this wave's k-quarter) into VGPRs ----
  const int bcol0 = nbase + (lane&15);
  const int bcol1 = bcol0 + 16;
  const int bk    = q_w*256 + (lane>>4)*8;
  f16x8 Bi0[8], Bi1[8], Bf0[8], Bf1[8];
  #pragma unroll
  for(int kk=0;kk<8;kk++){
    Bi0[kk] = *reinterpret_cast<const f16x8*>(wTi + bcol0*1024 + bk + kk*32);
    Bi1[kk] = *reinterpret_cast<const f16x8*>(wTi + bcol1*1024 + bk + kk*32);
    Bf0[kk] = *reinterpret_cast<const f16x8*>(wTf + bcol0*1024 + bk + kk*32);
    Bf1[kk] = *reinterpret_cast<const f16x8*>(wTf + bcol1*1024 + bk + kk*32);
  }

  const int b_l = tid >> 4;            // owned batch row 0..31
  const int h_l = (tid & 15)*2;        // owned col pair in slice
  const int bg  = mbase + b_l;

  float tT[3][3][2];
  { const float* Tp[3] = {Ti, Tf, Tc};
    #pragma unroll
    for(int g=0; g<3; g++)
      #pragma unroll
      for(int v=0; v<3; v++)
        #pragma unroll
        for(int j=0; j<2; j++) tT[g][v][j] = Tp[g][v*1024 + nbase + h_l + j];
  }
  float cm0 = 0.f, cm1 = 0.f;          // master c in f32

  const int arow = mh_w*16 + (lane&15);
  const int aoff = q_w*256 + ((lane>>4)<<3);

  int vc = x[bg*512];

  for(int t=0; t<NSTEP; t++){
    const bool last = (t == NSTEP-1);
    const unsigned* rdp = cpl + (unsigned)(t&1)*262144u;
    unsigned*       wrp = cpl + (unsigned)((t+1)&1)*262144u;
    const unsigned texp = ((unsigned)t) << 16;

    // ---- poll-load A: accept only when every u32's tag == t ----
    u32x4 r[16];
    const unsigned* ap = rdp + (mbase+arow)*1024 + aoff;
    while(true){
      ldA16_coh(ap, r);
      unsigned acc = 0u;
      #pragma unroll
      for(int i=0;i<16;i++){
        acc |= (r[i][0]^texp); acc |= (r[i][1]^texp);
        acc |= (r[i][2]^texp); acc |= (r[i][3]^texp);
      }
      if(__all((int)((acc & 0xFFFF0000u) == 0u))) break;
      __builtin_amdgcn_s_sleep(1);
    }
    int vn = last ? 0 : x[bg*512 + t + 1];

    // ---- unpack low f16 halves -> 8 A fragments (v_perm) ----
    f16x8 ah[8];
    #pragma unroll
    for(int kk=0;kk<8;kk++){
      union { unsigned u[4]; f16x8 v; } uu;
      uu.u[0] = __builtin_amdgcn_perm(r[2*kk][1],   r[2*kk][0],   0x05040100u);
      uu.u[1] = __builtin_amdgcn_perm(r[2*kk][3],   r[2*kk][2],   0x05040100u);
      uu.u[2] = __builtin_amdgcn_perm(r[2*kk+1][1], r[2*kk+1][0], 0x05040100u);
      uu.u[3] = __builtin_amdgcn_perm(r[2*kk+1][3], r[2*kk+1][2], 0x05040100u);
      ah[kk] = uu.v;
    }

    // ---- 32 MFMA: i,f gates x 2 col-halves x 8 k-slices ----
    f32x4 a00={0.f,0.f,0.f,0.f}, a01={0.f,0.f,0.f,0.f};
    f32x4 a10={0.f,0.f,0.f,0.f}, a11={0.f,0.f,0.f,0.f};
    #pragma unroll
    for(int kk=0;kk<8;kk++){
      a00 = __builtin_amdgcn_mfma_f32_16x16x32_f16(ah[kk], Bi0[kk], a00, 0,0,0);
      a01 = __builtin_amdgcn_mfma_f32_16x16x32_f16(ah[kk], Bi1[kk], a01, 0,0,0);
      a10 = __builtin_amdgcn_mfma_f32_16x16x32_f16(ah[kk], Bf0[kk], a10, 0,0,0);
      a11 = __builtin_amdgcn_mfma_f32_16x16x32_f16(ah[kk], Bf1[kk], a11, 0,0,0);
    }
    *reinterpret_cast<f32x4*>(xch + (wid*4 + 0)*256 + lane*4) = a00;
    *reinterpret_cast<f32x4*>(xch + (wid*4 + 1)*256 + lane*4) = a01;
    *reinterpret_cast<f32x4*>(xch + (wid*4 + 2)*256 + lane*4) = a10;
    *reinterpret_cast<f32x4*>(xch + (wid*4 + 3)*256 + lane*4) = a11;
    if(last){
      f32x4 o0={0.f,0.f,0.f,0.f}, o1={0.f,0.f,0.f,0.f};
      #pragma unroll
      for(int kk=0;kk<8;kk++){
        f16x8 bo0 = *reinterpret_cast<const f16x8*>(wTo + bcol0*1024 + bk + kk*32);
        f16x8 bo1 = *reinterpret_cast<const f16x8*>(wTo + bcol1*1024 + bk + kk*32);
        o0 = __builtin_amdgcn_mfma_f32_16x16x32_f16(ah[kk], bo0, o0, 0,0,0);
        o1 = __builtin_amdgcn_mfma_f32_16x16x32_f16(ah[kk], bo1, o1, 0,0,0);
      }
      *reinterpret_cast<f32x4*>(xo + (wid*2 + 0)*256 + lane*4) = o0;
      *reinterpret_cast<f32x4*>(xo + (wid*2 + 1)*256 + lane*4) = o1;
    }
    __syncthreads();   // the only barrier per step

    // ---- elementwise update: each thread owns 2 c elements ----
    {
      const int v = vc;
      int r16 = b_l & 15;
      int mh  = b_l >> 4;
      int reg = r16 & 3;
      int lq  = r16 >> 2;
      float cn[2], hh[2];
      #pragma unroll
      for(int j=0;j<2;j++){
        int col = h_l + j;
        int nh  = col >> 4;
        int l   = (lq<<4) | (col & 15);
        float mi = 0.f, mf = 0.f;
        #pragma unroll
        for(int q=0;q<4;q++){
          const float* base = xch + ((q*2+mh)*4 + nh)*256 + l*4 + reg;
          mi += base[0];
          mf += base[512];
        }
        float ti = (v==0)?tT[0][0][j]:(v==1)?tT[0][1][j]:tT[0][2][j];
        float tf = (v==0)?tT[1][0][j]:(v==1)?tT[1][1][j]:tT[1][2][j];
        float tc = (v==0)?tT[2][0][j]:(v==1)?tT[2][1][j]:tT[2][2][j];
        float iv = sigf(ti + mi);
        float fv = sigf(tf + mf);
        float cv = sigf(tc);
        float cm = j ? cm1 : cm0;
        float c2 = cv*iv + cm*fv;
        cn[j] = c2;
        if(last){
          float mo = 0.f;
          #pragma unroll
          for(int q=0;q<4;q++) mo += xo[((q*2+mh)*2 + nh)*256 + l*4 + reg];
          float to = To[v*1024 + nbase + col];
          float ov = sigf(to + mo);
          float pad = (float)((v+1)>>1);
          hh[j] = tanhf(c2)*ov*pad;
        }
      }
      if(!last){
        cm0 = cn[0]; cm1 = cn[1];
        unsigned tp = ((unsigned)(t+1)) << 16;
        unsigned p0 = tp | (unsigned)f2h(cn[0]);
        unsigned p1 = tp | (unsigned)f2h(cn[1]);
        st64_coh(wrp + bg*1024 + nbase + h_l, p0, p1);
      } else {
        *reinterpret_cast<float2*>(hbuf + bg*1024 + nbase + h_l) = make_float2(hh[0], hh[1]);
      }
    }
    vc = vn;
  }
}

// ---- projection + log_softmax over axis 0 (batch) ----
__global__ void k_proj(const float* __restrict__ hbuf, const float* __restrict__ w_ph,
                       const float* __restrict__ b_p, float* __restrict__ out){
  const int c = blockIdx.x;    // 0..9
  const int b = threadIdx.x;   // 0..255
  float acc = b_p[c];
  const float4* hb = reinterpret_cast<const float4*>(hbuf + b*1024);
  for(int i=0;i<256;i++){
    float4 hv = hb[i];
    int h = i*4;
    acc += hv.x*w_ph[h*10+c] + hv.y*w_ph[(h+1)*10+c] + hv.z*w_ph[(h+2)*10+c] + hv.w*w_ph[(h+3)*10+c];
  }
  __shared__ float red[256];
  red[b] = acc; __syncthreads();
  for(int s=128;s>0;s>>=1){ if(b<s) red[b]=fmaxf(red[b],red[b+s]); __syncthreads(); }
  float m = red[0]; __syncthreads();
  red[b] = expf(acc-m); __syncthreads();
  for(int s=128;s>0;s>>=1){ if(b<s) red[b]+=red[b+s]; __syncthreads(); }
  out[b*10+c] = acc - m - logf(red[0]);
}

extern "C" void kernel_launch(void* const* d_in, const int* in_sizes, int n_in,
                              void* d_out, int out_size, void* d_ws, size_t ws_size,
                              hipStream_t stream){
  const int*   x    = (const int*)  d_in[0];
  const float* emb  = (const float*)d_in[1];
  const float* w_cx = (const float*)d_in[2];
  const float* b_c  = (const float*)d_in[3];
  const float* w_ix = (const float*)d_in[4];
  const float* w_ih = (const float*)d_in[5];
  const float* b_i  = (const float*)d_in[6];
  const float* w_fx = (const float*)d_in[7];
  const float* w_fh = (const float*)d_in[8];
  const float* b_f  = (const float*)d_in[9];
  const float* w_ox = (const float*)d_in[10];
  const float* w_oh = (const float*)d_in[11];
  const float* b_o  = (const float*)d_in[12];
  const float* w_ph = (const float*)d_in[13];
  const float* b_p  = (const float*)d_in[14];
  float* out = (float*)d_out;

  char* ws = (char*)d_ws;
  float* Ti = (float*)(ws);
  float* Tf = (float*)(ws + 12288);
  float* To = (float*)(ws + 24576);
  float* Tc = (float*)(ws + 36864);
  unsigned short* wTi = (unsigned short*)(ws + 49152);
  unsigned short* wTf = (unsigned short*)(ws + 2146304);
  unsigned short* wTo = (unsigned short*)(ws + 4243456);
  unsigned* cpl = (unsigned*)(ws + 6340608);   // 2 planes x 1MB u32 (tagged)
  float* hbuf = (float*)(ws + 8437760);        // 1MB

  hipMemsetAsync(cpl, 0, 2097152, stream);     // tag 0 everywhere; plane0 = c0 data
  k_tables<<<4,256,0,stream>>>(emb, w_ix, b_i, Ti);
  k_tables<<<4,256,0,stream>>>(emb, w_fx, b_f, Tf);
  k_tables<<<4,256,0,stream>>>(emb, w_ox, b_o, To);
  k_tables<<<4,256,0,stream>>>(emb, w_cx, b_c, Tc);
  k_transpose<<<256,256,0,stream>>>(w_ih, wTi);
  k_transpose<<<256,256,0,stream>>>(w_fh, wTf);
  k_transpose<<<256,256,0,stream>>>(w_oh, wTo);

  void* args[] = { (void*)&x, (void*)&wTi, (void*)&wTf, (void*)&wTo,
                   (void*)&Ti, (void*)&Tf, (void*)&To, (void*)&Tc,
                   (void*)&cpl, (void*)&hbuf };
  (void)hipLaunchCooperativeKernel((void*)k_recur, dim3(256), dim3(512), args, 0, stream);
  k_proj<<<10,256,0,stream>>>(hbuf, w_ph, b_p, out);
}

// Round 9
// 5176.081 us; speedup vs baseline: 1.2212x; 1.2212x over previous
//
#include <hip/hip_runtime.h>
#include <hip/hip_bf16.h>
#include <hip/hip_fp16.h>

typedef __attribute__((ext_vector_type(8))) _Float16 f16x8;
typedef __attribute__((ext_vector_type(4))) float f32x4;

#define NSTEP 511

__device__ __forceinline__ unsigned short f2h(float f){ return __half_as_ushort(__float2half(f)); }
__device__ __forceinline__ float sigf(float z){ return 1.0f/(1.0f + __expf(-z)); }

// Coherent ops (sc0 sc1): validated protocol from round 5.
__device__ __forceinline__ void st32_coh_nw(unsigned* p, unsigned v){
  asm volatile("global_store_dword %0, %1, off sc0 sc1" :: "v"(p), "v"(v) : "memory");
}
__device__ __forceinline__ unsigned ld32_coh(const unsigned* p){
  unsigned v;
  asm volatile("global_load_dword %0, %1, off sc0 sc1\n\ts_waitcnt vmcnt(0)"
               : "=v"(v) : "v"(p) : "memory");
  return v;
}
// 8x16B coherent loads (lane's 128B A-slice) + in-block waitcnt.
__device__ __forceinline__ void ldA8_coh(const void* p, f16x8 a[8]){
  asm volatile(
    "global_load_dwordx4 %0, %8, off sc0 sc1\n\t"
    "global_load_dwordx4 %1, %8, off offset:64 sc0 sc1\n\t"
    "global_load_dwordx4 %2, %8, off offset:128 sc0 sc1\n\t"
    "global_load_dwordx4 %3, %8, off offset:192 sc0 sc1\n\t"
    "global_load_dwordx4 %4, %8, off offset:256 sc0 sc1\n\t"
    "global_load_dwordx4 %5, %8, off offset:320 sc0 sc1\n\t"
    "global_load_dwordx4 %6, %8, off offset:384 sc0 sc1\n\t"
    "global_load_dwordx4 %7, %8, off offset:448 sc0 sc1\n\t"
    "s_waitcnt vmcnt(0)"
    : "=v"(a[0]),"=v"(a[1]),"=v"(a[2]),"=v"(a[3]),
      "=v"(a[4]),"=v"(a[5]),"=v"(a[6]),"=v"(a[7])
    : "v"(p) : "memory");
}

// ---- gate tables: T[v][h] = sum_e emb[v,e]*w[e,h] + b[h], v in 0..2 ----
__global__ void k_tables(const float* __restrict__ emb, const float* __restrict__ w,
                         const float* __restrict__ bias, float* __restrict__ T){
  int h = blockIdx.x*256 + threadIdx.x;
  float a0=0.f, a1=0.f, a2=0.f;
  for(int e=0;e<512;e++){
    float we = w[e*1024 + h];
    a0 += emb[e]*we; a1 += emb[512+e]*we; a2 += emb[1024+e]*we;
  }
  float b = bias[h];
  T[h] = a0+b; T[1024+h] = a1+b; T[2048+h] = a2+b;
}

// ---- transpose 1024x1024 f32 -> f16 wT[n][k] = w[k][n] ----
__global__ void k_transpose(const float* __restrict__ w, unsigned short* __restrict__ wT){
  __shared__ float tile[64][65];
  int tr = blockIdx.x & 15, tc = blockIdx.x >> 4;
  int col = threadIdx.x & 63;
  int r0  = threadIdx.x >> 6;
  for(int rr=0; rr<16; rr++){
    int row = rr*4 + r0;
    tile[row][col] = w[(tr*64+row)*1024 + tc*64 + col];
  }
  __syncthreads();
  for(int rr=0; rr<16; rr++){
    int row = rr*4 + r0;
    wT[(tc*64+row)*1024 + tr*64 + col] = f2h(tile[col][row]);
  }
}

// ---- sequential recurrence: 256 WGs = 8 batch-groups x 32 col-slices ----
// r5 structure + per-wave flags (no 2nd barrier, no tid0 hop), parity-
// double-buffered xch, hard-spin poll. One __syncthreads per step.
// Wave wid = q*2 + mh: k-quarter q, 16-row half mh.
// flags[mg*256 + ng*8 + wid] = t+1 after wave's publishes of step t drained.
__global__ void __launch_bounds__(512,1) k_recur(
    const int* __restrict__ x,
    const unsigned short* __restrict__ wTi,   // w_ih^T f16 [n][k]
    const unsigned short* __restrict__ wTf,
    const unsigned short* __restrict__ wTo,
    const float* __restrict__ Ti, const float* __restrict__ Tf,
    const float* __restrict__ To, const float* __restrict__ Tc,
    unsigned short* __restrict__ cbf,         // [2][256][1024] f16 planes
    float* __restrict__ hbuf,
    unsigned* __restrict__ bars)              // [8 grp][32 ng][8 wid] flags
{
  __shared__ __align__(16) float xch[16384];  // 2 x 32KB (step parity)
  __shared__ __align__(16) float xo[4096];    // 16KB o-gate (last step only)

  const int tid  = threadIdx.x;
  const int wid  = tid >> 6;
  const int lane = tid & 63;
  const int mg   = blockIdx.x & 7;
  const int ng   = blockIdx.x >> 3;
  const int mbase = mg*32;
  const int nbase = ng*32;

  const int mh_w = wid & 1;
  const int q_w  = wid >> 1;

  // ---- B (i,f gates; both 16-col halves; this wave's k-quarter) into VGPRs ----
  const int bcol0 = nbase + (lane&15);
  const int bcol1 = bcol0 + 16;
  const int bk    = q_w*256 + (lane>>4)*8;
  f16x8 Bi0[8], Bi1[8], Bf0[8], Bf1[8];
  #pragma unroll
  for(int kk=0;kk<8;kk++){
    Bi0[kk] = *reinterpret_cast<const f16x8*>(wTi + bcol0*1024 + bk + kk*32);
    Bi1[kk] = *reinterpret_cast<const f16x8*>(wTi + bcol1*1024 + bk + kk*32);
    Bf0[kk] = *reinterpret_cast<const f16x8*>(wTf + bcol0*1024 + bk + kk*32);
    Bf1[kk] = *reinterpret_cast<const f16x8*>(wTf + bcol1*1024 + bk + kk*32);
  }

  const int b_l = tid >> 4;            // owned batch row 0..31
  const int h_l = (tid & 15)*2;        // owned col pair in slice
  const int bg  = mbase + b_l;

  float tT[3][3][2];
  { const float* Tp[3] = {Ti, Tf, Tc};
    #pragma unroll
    for(int g=0; g<3; g++)
      #pragma unroll
      for(int v=0; v<3; v++)
        #pragma unroll
        for(int j=0; j<2; j++) tT[g][v][j] = Tp[g][v*1024 + nbase + h_l + j];
  }
  float cm0 = 0.f, cm1 = 0.f;          // master c in f32

  const int arow = mh_w*16 + (lane&15);          // row within group
  const int aoff = q_w*256 + ((lane>>4)<<3);     // element offset within row
  const unsigned* pollp = bars + (mg*256 + q_w*64 + lane);   // 1 flag per lane
  unsigned* flagp = bars + (mg*256 + ng*8 + wid);

  int vc = x[bg*512];

  for(int t=0; t<NSTEP; t++){
    const bool last = (t == NSTEP-1);
    const unsigned short* rdp = cbf + (unsigned)(t&1)*262144u;
    unsigned short*       wrp = cbf + (unsigned)((t+1)&1)*262144u;

    // ---- per-wave poll: 64 producer-wave flags of this wave's k-quarter ----
    if(t > 0){
      const unsigned tgt = (unsigned)t;
      while(true){
        unsigned v = ld32_coh(pollp);
        if(__all((int)(v >= tgt))) break;
      }
    }

    // ---- A fragments straight from the coherent plane ----
    f16x8 ah[8];
    ldA8_coh(rdp + (mbase + arow)*1024 + aoff, ah);
    int vn = last ? 0 : x[bg*512 + t + 1];

    // ---- 32 MFMA: i,f gates x 2 col-halves x 8 k-slices ----
    f32x4 a00={0.f,0.f,0.f,0.f}, a01={0.f,0.f,0.f,0.f};
    f32x4 a10={0.f,0.f,0.f,0.f}, a11={0.f,0.f,0.f,0.f};
    #pragma unroll
    for(int kk=0;kk<8;kk++){
      a00 = __builtin_amdgcn_mfma_f32_16x16x32_f16(ah[kk], Bi0[kk], a00, 0,0,0);
      a01 = __builtin_amdgcn_mfma_f32_16x16x32_f16(ah[kk], Bi1[kk], a01, 0,0,0);
      a10 = __builtin_amdgcn_mfma_f32_16x16x32_f16(ah[kk], Bf0[kk], a10, 0,0,0);
      a11 = __builtin_amdgcn_mfma_f32_16x16x32_f16(ah[kk], Bf1[kk], a11, 0,0,0);
    }
    float* xb = xch + (unsigned)(t&1)*8192u;
    *reinterpret_cast<f32x4*>(xb + (wid*4 + 0)*256 + lane*4) = a00;
    *reinterpret_cast<f32x4*>(xb + (wid*4 + 1)*256 + lane*4) = a01;
    *reinterpret_cast<f32x4*>(xb + (wid*4 + 2)*256 + lane*4) = a10;
    *reinterpret_cast<f32x4*>(xb + (wid*4 + 3)*256 + lane*4) = a11;
    if(last){
      f32x4 o0={0.f,0.f,0.f,0.f}, o1={0.f,0.f,0.f,0.f};
      #pragma unroll
      for(int kk=0;kk<8;kk++){
        f16x8 bo0 = *reinterpret_cast<const f16x8*>(wTo + bcol0*1024 + bk + kk*32);
        f16x8 bo1 = *reinterpret_cast<const f16x8*>(wTo + bcol1*1024 + bk + kk*32);
        o0 = __builtin_amdgcn_mfma_f32_16x16x32_f16(ah[kk], bo0, o0, 0,0,0);
        o1 = __builtin_amdgcn_mfma_f32_16x16x32_f16(ah[kk], bo1, o1, 0,0,0);
      }
      *reinterpret_cast<f32x4*>(xo + (wid*2 + 0)*256 + lane*4) = o0;
      *reinterpret_cast<f32x4*>(xo + (wid*2 + 1)*256 + lane*4) = o1;
    }
    __syncthreads();   // the only barrier per step

    // ---- elementwise update: each thread owns 2 c elements ----
    {
      const int v = vc;
      int r16 = b_l & 15;
      int mh  = b_l >> 4;
      int reg = r16 & 3;
      int lq  = r16 >> 2;
      float cn[2], hh[2];
      #pragma unroll
      for(int j=0;j<2;j++){
        int col = h_l + j;
        int nh  = col >> 4;
        int l   = (lq<<4) | (col & 15);
        float mi = 0.f, mf = 0.f;
        #pragma unroll
        for(int q=0;q<4;q++){
          const float* base = xb + ((q*2+mh)*4 + nh)*256 + l*4 + reg;
          mi += base[0];
          mf += base[512];
        }
        float ti = (v==0)?tT[0][0][j]:(v==1)?tT[0][1][j]:tT[0][2][j];
        float tf = (v==0)?tT[1][0][j]:(v==1)?tT[1][1][j]:tT[1][2][j];
        float tc = (v==0)?tT[2][0][j]:(v==1)?tT[2][1][j]:tT[2][2][j];
        float iv = sigf(ti + mi);
        float fv = sigf(tf + mf);
        float cv = sigf(tc);
        float cm = j ? cm1 : cm0;
        float c2 = cv*iv + cm*fv;
        cn[j] = c2;
        if(last){
          float mo = 0.f;
          #pragma unroll
          for(int q=0;q<4;q++) mo += xo[((q*2+mh)*2 + nh)*256 + l*4 + reg];
          float to = To[v*1024 + nbase + col];
          float ov = sigf(to + mo);
          float pad = (float)((v+1)>>1);
          hh[j] = tanhf(c2)*ov*pad;
        }
      }
      if(!last){
        cm0 = cn[0]; cm1 = cn[1];
        unsigned pk = (unsigned)f2h(cn[0]) | (((unsigned)f2h(cn[1]))<<16);
        st32_coh_nw(reinterpret_cast<unsigned*>(wrp + bg*1024 + nbase + h_l), pk);
      } else {
        *reinterpret_cast<float2*>(hbuf + bg*1024 + nbase + h_l) = make_float2(hh[0], hh[1]);
      }
    }

    if(!last){
      // wave-level drain of this wave's 64 publish stores, then its flag
      asm volatile("s_waitcnt vmcnt(0)" ::: "memory");
      if(lane == 0) st32_coh_nw(flagp, (unsigned)(t+1));
    }
    vc = vn;
  }
}

// ---- projection + log_softmax over axis 0 (batch) ----
__global__ void k_proj(const float* __restrict__ hbuf, const float* __restrict__ w_ph,
                       const float* __restrict__ b_p, float* __restrict__ out){
  const int c = blockIdx.x;    // 0..9
  const int b = threadIdx.x;   // 0..255
  float acc = b_p[c];
  const float4* hb = reinterpret_cast<const float4*>(hbuf + b*1024);
  for(int i=0;i<256;i++){
    float4 hv = hb[i];
    int h = i*4;
    acc += hv.x*w_ph[h*10+c] + hv.y*w_ph[(h+1)*10+c] + hv.z*w_ph[(h+2)*10+c] + hv.w*w_ph[(h+3)*10+c];
  }
  __shared__ float red[256];
  red[b] = acc; __syncthreads();
  for(int s=128;s>0;s>>=1){ if(b<s) red[b]=fmaxf(red[b],red[b+s]); __syncthreads(); }
  float m = red[0]; __syncthreads();
  red[b] = expf(acc-m); __syncthreads();
  for(int s=128;s>0;s>>=1){ if(b<s) red[b]+=red[b+s]; __syncthreads(); }
  out[b*10+c] = acc - m - logf(red[0]);
}

extern "C" void kernel_launch(void* const* d_in, const int* in_sizes, int n_in,
                              void* d_out, int out_size, void* d_ws, size_t ws_size,
                              hipStream_t stream){
  const int*   x    = (const int*)  d_in[0];
  const float* emb  = (const float*)d_in[1];
  const float* w_cx = (const float*)d_in[2];
  const float* b_c  = (const float*)d_in[3];
  const float* w_ix = (const float*)d_in[4];
  const float* w_ih = (const float*)d_in[5];
  const float* b_i  = (const float*)d_in[6];
  const float* w_fx = (const float*)d_in[7];
  const float* w_fh = (const float*)d_in[8];
  const float* b_f  = (const float*)d_in[9];
  const float* w_ox = (const float*)d_in[10];
  const float* w_oh = (const float*)d_in[11];
  const float* b_o  = (const float*)d_in[12];
  const float* w_ph = (const float*)d_in[13];
  const float* b_p  = (const float*)d_in[14];
  float* out = (float*)d_out;

  char* ws = (char*)d_ws;
  float* Ti = (float*)(ws);
  float* Tf = (float*)(ws + 12288);
  float* To = (float*)(ws + 24576);
  float* Tc = (float*)(ws + 36864);
  unsigned short* wTi = (unsigned short*)(ws + 49152);
  unsigned short* wTf = (unsigned short*)(ws + 2146304);
  unsigned short* wTo = (unsigned short*)(ws + 4243456);
  unsigned short* cbf = (unsigned short*)(ws + 6340608);  // 2 planes x 512KB f16
  unsigned* bars = (unsigned*)(ws + 7389184);             // 8 grp x 256 wave-flags
  float* hbuf = (float*)(ws + 7397376);                   // 1MB

  hipMemsetAsync(cbf, 0, 1048576 + 8192, stream);   // c planes + wave flags
  k_tables<<<4,256,0,stream>>>(emb, w_ix, b_i, Ti);
  k_tables<<<4,256,0,stream>>>(emb, w_fx, b_f, Tf);
  k_tables<<<4,256,0,stream>>>(emb, w_ox, b_o, To);
  k_tables<<<4,256,0,stream>>>(emb, w_cx, b_c, Tc);
  k_transpose<<<256,256,0,stream>>>(w_ih, wTi);
  k_transpose<<<256,256,0,stream>>>(w_fh, wTf);
  k_transpose<<<256,256,0,stream>>>(w_oh, wTo);

  void* args[] = { (void*)&x, (void*)&wTi, (void*)&wTf, (void*)&wTo,
                   (void*)&Ti, (void*)&Tf, (void*)&To, (void*)&Tc,
                   (void*)&cbf, (void*)&hbuf, (void*)&bars };
  (void)hipLaunchCooperativeKernel((void*)k_recur, dim3(256), dim3(512), args, 0, stream);
  k_proj<<<10,256,0,stream>>>(hbuf, w_ph, b_p, out);
}

// Round 11
// 4502.612 us; speedup vs baseline: 1.4038x; 1.1496x over previous
//
#include <hip/hip_runtime.h>
#include <hip/hip_bf16.h>
#include <hip/hip_fp16.h>

typedef __attribute__((ext_vector_type(8))) _Float16 f16x8;
typedef __attribute__((ext_vector_type(4))) float f32x4;

#define NSTEP 511

__device__ __forceinline__ unsigned short f2h(float f){ return __half_as_ushort(__float2half(f)); }
__device__ __forceinline__ float sigf(float z){ return 1.0f/(1.0f + __expf(-z)); }

// Coherent ops (sc0 sc1): L1/L2-bypass; memory-side L3 is the coherent point.
__device__ __forceinline__ void st32_coh_nw(unsigned* p, unsigned v){
  asm volatile("global_store_dword %0, %1, off sc0 sc1" :: "v"(p), "v"(v) : "memory");
}
__device__ __forceinline__ unsigned ld32_coh(const unsigned* p){
  unsigned v;
  asm volatile("global_load_dword %0, %1, off sc0 sc1\n\ts_waitcnt vmcnt(0)"
               : "=v"(v) : "v"(p) : "memory");
  return v;
}
// 8x16B coherent loads (lane's 128B A-slice) + in-block waitcnt.
// "=&v" early-clobber: outputs must not alias the address register.
__device__ __forceinline__ void ldA8_coh(const void* p, f16x8 a[8]){
  asm volatile(
    "global_load_dwordx4 %0, %8, off sc0 sc1\n\t"
    "global_load_dwordx4 %1, %8, off offset:64 sc0 sc1\n\t"
    "global_load_dwordx4 %2, %8, off offset:128 sc0 sc1\n\t"
    "global_load_dwordx4 %3, %8, off offset:192 sc0 sc1\n\t"
    "global_load_dwordx4 %4, %8, off offset:256 sc0 sc1\n\t"
    "global_load_dwordx4 %5, %8, off offset:320 sc0 sc1\n\t"
    "global_load_dwordx4 %6, %8, off offset:384 sc0 sc1\n\t"
    "global_load_dwordx4 %7, %8, off offset:448 sc0 sc1\n\t"
    "s_waitcnt vmcnt(0)"
    : "=&v"(a[0]),"=&v"(a[1]),"=&v"(a[2]),"=&v"(a[3]),
      "=&v"(a[4]),"=&v"(a[5]),"=&v"(a[6]),"=&v"(a[7])
    : "v"(p) : "memory");
}

// ---- gate tables: T[v][h] = sum_e emb[v,e]*w[e,h] + b[h], v in 0..2 ----
__global__ void k_tables(const float* __restrict__ emb, const float* __restrict__ w,
                         const float* __restrict__ bias, float* __restrict__ T){
  int h = blockIdx.x*256 + threadIdx.x;
  float a0=0.f, a1=0.f, a2=0.f;
  for(int e=0;e<512;e++){
    float we = w[e*1024 + h];
    a0 += emb[e]*we; a1 += emb[512+e]*we; a2 += emb[1024+e]*we;
  }
  float b = bias[h];
  T[h] = a0+b; T[1024+h] = a1+b; T[2048+h] = a2+b;
}

// ---- transpose 1024x1024 f32 -> f16 wT[n][k] = w[k][n] ----
__global__ void k_transpose(const float* __restrict__ w, unsigned short* __restrict__ wT){
  __shared__ float tile[64][65];
  int tr = blockIdx.x & 15, tc = blockIdx.x >> 4;
  int col = threadIdx.x & 63;
  int r0  = threadIdx.x >> 6;
  for(int rr=0; rr<16; rr++){
    int row = rr*4 + r0;
    tile[row][col] = w[(tr*64+row)*1024 + tc*64 + col];
  }
  __syncthreads();
  for(int rr=0; rr<16; rr++){
    int row = rr*4 + r0;
    wT[(tc*64+row)*1024 + tr*64 + col] = f2h(tile[col][row]);
  }
}

// ---- sequential recurrence: 256 WGs = 8 batch-groups x 32 col-slices ----
// r5 protocol (poll 8 WG-flags -> A-load -> MFMA -> xch -> barrier -> update
// -> publish) with: single barrier/step (LDS wave-counter elects the flag
// publisher), parity-double-buffered xch, early-clobber A-load asm.
// Wave wid = q*2 + mh: k-quarter q, 16-row half mh.
__global__ void __launch_bounds__(512,1) k_recur(
    const int* __restrict__ x,
    const unsigned short* __restrict__ wTi,   // w_ih^T f16 [n][k]
    const unsigned short* __restrict__ wTf,
    const unsigned short* __restrict__ wTo,
    const float* __restrict__ Ti, const float* __restrict__ Tf,
    const float* __restrict__ To, const float* __restrict__ Tc,
    unsigned short* __restrict__ cbf,         // [2][256][1024] f16 planes
    float* __restrict__ hbuf,
    unsigned* __restrict__ bars)              // [8 grp][32 ng] WG flags
{
  __shared__ __align__(16) float xch[16384];  // 2 x 32KB (step parity)
  __shared__ __align__(16) float xo[4096];    // 16KB o-gate (last step only)
  __shared__ unsigned wcnt;                   // monotonic wave-publish counter

  const int tid  = threadIdx.x;
  const int wid  = tid >> 6;
  const int lane = tid & 63;
  const int mg   = blockIdx.x & 7;
  const int ng   = blockIdx.x >> 3;
  const int mbase = mg*32;
  const int nbase = ng*32;

  const int mh_w = wid & 1;
  const int q_w  = wid >> 1;

  if(tid == 0) wcnt = 0u;   // first use is after step-0's barrier -> ordered

  // ---- B (i,f gates; both 16-col halves; this wave's k-quarter) into VGPRs ----
  const int bcol0 = nbase + (lane&15);
  const int bcol1 = bcol0 + 16;
  const int bk    = q_w*256 + (lane>>4)*8;
  f16x8 Bi0[8], Bi1[8], Bf0[8], Bf1[8];
  #pragma unroll
  for(int kk=0;kk<8;kk++){
    Bi0[kk] = *reinterpret_cast<const f16x8*>(wTi + bcol0*1024 + bk + kk*32);
    Bi1[kk] = *reinterpret_cast<const f16x8*>(wTi + bcol1*1024 + bk + kk*32);
    Bf0[kk] = *reinterpret_cast<const f16x8*>(wTf + bcol0*1024 + bk + kk*32);
    Bf1[kk] = *reinterpret_cast<const f16x8*>(wTf + bcol1*1024 + bk + kk*32);
  }

  const int b_l = tid >> 4;            // owned batch row 0..31
  const int h_l = (tid & 15)*2;        // owned col pair in slice
  const int bg  = mbase + b_l;

  float tT[3][3][2];
  { const float* Tp[3] = {Ti, Tf, Tc};
    #pragma unroll
    for(int g=0; g<3; g++)
      #pragma unroll
      for(int v=0; v<3; v++)
        #pragma unroll
        for(int j=0; j<2; j++) tT[g][v][j] = Tp[g][v*1024 + nbase + h_l + j];
  }
  float cm0 = 0.f, cm1 = 0.f;          // master c in f32

  const int arow = mh_w*16 + (lane&15);          // row within group
  const int aoff = q_w*256 + ((lane>>4)<<3);     // element offset within row
  const unsigned* pollp = bars + (mg*32 + q_w*8 + (lane&7));  // 8 producer flags
  unsigned* flagp = bars + (mg*32 + ng);

  int vc = x[bg*512];

  for(int t=0; t<NSTEP; t++){
    const bool last = (t == NSTEP-1);
    const unsigned short* rdp = cbf + (unsigned)(t&1)*262144u;
    unsigned short*       wrp = cbf + (unsigned)((t+1)&1)*262144u;

    // ---- per-wave poll: 8 producer WGs of this wave's k-quarter ----
    if(t > 0){
      const unsigned tgt = (unsigned)t;
      while(true){
        unsigned v = ld32_coh(pollp);
        if(__all((int)(v >= tgt))) break;
        __builtin_amdgcn_s_sleep(1);
      }
    }

    // ---- A fragments straight from the coherent plane ----
    f16x8 ah[8];
    ldA8_coh(rdp + (mbase + arow)*1024 + aoff, ah);
    int vn = last ? 0 : x[bg*512 + t + 1];

    // ---- 32 MFMA: i,f gates x 2 col-halves x 8 k-slices ----
    f32x4 a00={0.f,0.f,0.f,0.f}, a01={0.f,0.f,0.f,0.f};
    f32x4 a10={0.f,0.f,0.f,0.f}, a11={0.f,0.f,0.f,0.f};
    #pragma unroll
    for(int kk=0;kk<8;kk++){
      a00 = __builtin_amdgcn_mfma_f32_16x16x32_f16(ah[kk], Bi0[kk], a00, 0,0,0);
      a01 = __builtin_amdgcn_mfma_f32_16x16x32_f16(ah[kk], Bi1[kk], a01, 0,0,0);
      a10 = __builtin_amdgcn_mfma_f32_16x16x32_f16(ah[kk], Bf0[kk], a10, 0,0,0);
      a11 = __builtin_amdgcn_mfma_f32_16x16x32_f16(ah[kk], Bf1[kk], a11, 0,0,0);
    }
    float* xb = xch + (unsigned)(t&1)*8192u;
    *reinterpret_cast<f32x4*>(xb + (wid*4 + 0)*256 + lane*4) = a00;
    *reinterpret_cast<f32x4*>(xb + (wid*4 + 1)*256 + lane*4) = a01;
    *reinterpret_cast<f32x4*>(xb + (wid*4 + 2)*256 + lane*4) = a10;
    *reinterpret_cast<f32x4*>(xb + (wid*4 + 3)*256 + lane*4) = a11;
    if(last){
      f32x4 o0={0.f,0.f,0.f,0.f}, o1={0.f,0.f,0.f,0.f};
      #pragma unroll
      for(int kk=0;kk<8;kk++){
        f16x8 bo0 = *reinterpret_cast<const f16x8*>(wTo + bcol0*1024 + bk + kk*32);
        f16x8 bo1 = *reinterpret_cast<const f16x8*>(wTo + bcol1*1024 + bk + kk*32);
        o0 = __builtin_amdgcn_mfma_f32_16x16x32_f16(ah[kk], bo0, o0, 0,0,0);
        o1 = __builtin_amdgcn_mfma_f32_16x16x32_f16(ah[kk], bo1, o1, 0,0,0);
      }
      *reinterpret_cast<f32x4*>(xo + (wid*2 + 0)*256 + lane*4) = o0;
      *reinterpret_cast<f32x4*>(xo + (wid*2 + 1)*256 + lane*4) = o1;
    }
    __syncthreads();   // the only barrier per step

    // ---- elementwise update: each thread owns 2 c elements ----
    {
      const int v = vc;
      int r16 = b_l & 15;
      int mh  = b_l >> 4;
      int reg = r16 & 3;
      int lq  = r16 >> 2;
      float cn[2], hh[2];
      #pragma unroll
      for(int j=0;j<2;j++){
        int col = h_l + j;
        int nh  = col >> 4;
        int l   = (lq<<4) | (col & 15);
        float mi = 0.f, mf = 0.f;
        #pragma unroll
        for(int q=0;q<4;q++){
          const float* base = xb + ((q*2+mh)*4 + nh)*256 + l*4 + reg;
          mi += base[0];
          mf += base[512];
        }
        float ti = (v==0)?tT[0][0][j]:(v==1)?tT[0][1][j]:tT[0][2][j];
        float tf = (v==0)?tT[1][0][j]:(v==1)?tT[1][1][j]:tT[1][2][j];
        float tc = (v==0)?tT[2][0][j]:(v==1)?tT[2][1][j]:tT[2][2][j];
        float iv = sigf(ti + mi);
        float fv = sigf(tf + mf);
        float cv = sigf(tc);
        float cm = j ? cm1 : cm0;
        float c2 = cv*iv + cm*fv;
        cn[j] = c2;
        if(last){
          float mo = 0.f;
          #pragma unroll
          for(int q=0;q<4;q++) mo += xo[((q*2+mh)*2 + nh)*256 + l*4 + reg];
          float to = To[v*1024 + nbase + col];
          float ov = sigf(to + mo);
          float pad = (float)((v+1)>>1);
          hh[j] = tanhf(c2)*ov*pad;
        }
      }
      if(!last){
        cm0 = cn[0]; cm1 = cn[1];
        unsigned pk = (unsigned)f2h(cn[0]) | (((unsigned)f2h(cn[1]))<<16);
        st32_coh_nw(reinterpret_cast<unsigned*>(wrp + bg*1024 + nbase + h_l), pk);
      } else {
        *reinterpret_cast<float2*>(hbuf + bg*1024 + nbase + h_l) = make_float2(hh[0], hh[1]);
      }
    }

    if(!last){
      // wave drains its 64 publish stores; 8th wave of this step posts the flag
      asm volatile("s_waitcnt vmcnt(0)" ::: "memory");
      if(lane == 0){
        unsigned old = atomicAdd(&wcnt, 1u);
        if(old == 8u*(unsigned)(t+1) - 1u)
          st32_coh_nw(flagp, (unsigned)(t+1));
      }
    }
    vc = vn;
  }
}

// ---- projection + log_softmax over axis 0 (batch) ----
__global__ void k_proj(const float* __restrict__ hbuf, const float* __restrict__ w_ph,
                       const float* __restrict__ b_p, float* __restrict__ out){
  const int c = blockIdx.x;    // 0..9
  const int b = threadIdx.x;   // 0..255
  float acc = b_p[c];
  const float4* hb = reinterpret_cast<const float4*>(hbuf + b*1024);
  for(int i=0;i<256;i++){
    float4 hv = hb[i];
    int h = i*4;
    acc += hv.x*w_ph[h*10+c] + hv.y*w_ph[(h+1)*10+c] + hv.z*w_ph[(h+2)*10+c] + hv.w*w_ph[(h+3)*10+c];
  }
  __shared__ float red[256];
  red[b] = acc; __syncthreads();
  for(int s=128;s>0;s>>=1){ if(b<s) red[b]=fmaxf(red[b],red[b+s]); __syncthreads(); }
  float m = red[0]; __syncthreads();
  red[b] = expf(acc-m); __syncthreads();
  for(int s=128;s>0;s>>=1){ if(b<s) red[b]+=red[b+s]; __syncthreads(); }
  out[b*10+c] = acc - m - logf(red[0]);
}

extern "C" void kernel_launch(void* const* d_in, const int* in_sizes, int n_in,
                              void* d_out, int out_size, void* d_ws, size_t ws_size,
                              hipStream_t stream){
  const int*   x    = (const int*)  d_in[0];
  const float* emb  = (const float*)d_in[1];
  const float* w_cx = (const float*)d_in[2];
  const float* b_c  = (const float*)d_in[3];
  const float* w_ix = (const float*)d_in[4];
  const float* w_ih = (const float*)d_in[5];
  const float* b_i  = (const float*)d_in[6];
  const float* w_fx = (const float*)d_in[7];
  const float* w_fh = (const float*)d_in[8];
  const float* b_f  = (const float*)d_in[9];
  const float* w_ox = (const float*)d_in[10];
  const float* w_oh = (const float*)d_in[11];
  const float* b_o  = (const float*)d_in[12];
  const float* w_ph = (const float*)d_in[13];
  const float* b_p  = (const float*)d_in[14];
  float* out = (float*)d_out;

  char* ws = (char*)d_ws;
  float* Ti = (float*)(ws);
  float* Tf = (float*)(ws + 12288);
  float* To = (float*)(ws + 24576);
  float* Tc = (float*)(ws + 36864);
  unsigned short* wTi = (unsigned short*)(ws + 49152);
  unsigned short* wTf = (unsigned short*)(ws + 2146304);
  unsigned short* wTo = (unsigned short*)(ws + 4243456);
  unsigned short* cbf = (unsigned short*)(ws + 6340608);  // 2 planes x 512KB f16
  unsigned* bars = (unsigned*)(ws + 7389184);             // 8 grp x 32 WG flags
  float* hbuf = (float*)(ws + 7391232);                   // 1MB

  hipMemsetAsync(cbf, 0, 1048576 + 2048, stream);   // c planes + flags
  k_tables<<<4,256,0,stream>>>(emb, w_ix, b_i, Ti);
  k_tables<<<4,256,0,stream>>>(emb, w_fx, b_f, Tf);
  k_tables<<<4,256,0,stream>>>(emb, w_ox, b_o, To);
  k_tables<<<4,256,0,stream>>>(emb, w_cx, b_c, Tc);
  k_transpose<<<256,256,0,stream>>>(w_ih, wTi);
  k_transpose<<<256,256,0,stream>>>(w_fh, wTf);
  k_transpose<<<256,256,0,stream>>>(w_oh, wTo);

  void* args[] = { (void*)&x, (void*)&wTi, (void*)&wTf, (void*)&wTo,
                   (void*)&Ti, (void*)&Tf, (void*)&To, (void*)&Tc,
                   (void*)&cbf, (void*)&hbuf, (void*)&bars };
  (void)hipLaunchCooperativeKernel((void*)k_recur, dim3(256), dim3(512), args, 0, stream);
  k_proj<<<10,256,0,stream>>>(hbuf, w_ph, b_p, out);
}

// Round 13
// 4074.984 us; speedup vs baseline: 1.5512x; 1.1049x over previous
//
#include <hip/hip_runtime.h>
#include <hip/hip_bf16.h>
#include <hip/hip_fp16.h>

typedef __attribute__((ext_vector_type(8))) _Float16 f16x8;
typedef __attribute__((ext_vector_type(4))) float f32x4;

#define NSTEP 511

__device__ __forceinline__ unsigned short f2h(float f){ return __half_as_ushort(__float2half(f)); }
__device__ __forceinline__ float sigf(float z){ return 1.0f/(1.0f + __expf(-z)); }

// Coherent ops (sc0 sc1): L1/L2-bypass; memory-side L3 is the coherent point.
__device__ __forceinline__ void st32_coh_nw(unsigned* p, unsigned v){
  asm volatile("global_store_dword %0, %1, off sc0 sc1" :: "v"(p), "v"(v) : "memory");
}
__device__ __forceinline__ unsigned ld32_coh(const unsigned* p){
  unsigned v;
  asm volatile("global_load_dword %0, %1, off sc0 sc1\n\ts_waitcnt vmcnt(0)"
               : "=v"(v) : "v"(p) : "memory");
  return v;
}
__device__ __forceinline__ int ldx(const int* p){
  int v;
  asm volatile("global_load_dword %0, %1, off\n\ts_waitcnt vmcnt(0)"
               : "=v"(v) : "v"(p) : "memory");
  return v;
}
// 16x16B coherent loads (both groups' 128B A-slices) + single in-block waitcnt.
__device__ __forceinline__ void ldA16_coh2(const void* p0, const void* p1,
                                           f16x8 a[8], f16x8 b[8]){
  asm volatile(
    "global_load_dwordx4 %0, %16, off sc0 sc1\n\t"
    "global_load_dwordx4 %1, %16, off offset:64 sc0 sc1\n\t"
    "global_load_dwordx4 %2, %16, off offset:128 sc0 sc1\n\t"
    "global_load_dwordx4 %3, %16, off offset:192 sc0 sc1\n\t"
    "global_load_dwordx4 %4, %16, off offset:256 sc0 sc1\n\t"
    "global_load_dwordx4 %5, %16, off offset:320 sc0 sc1\n\t"
    "global_load_dwordx4 %6, %16, off offset:384 sc0 sc1\n\t"
    "global_load_dwordx4 %7, %16, off offset:448 sc0 sc1\n\t"
    "global_load_dwordx4 %8, %17, off sc0 sc1\n\t"
    "global_load_dwordx4 %9, %17, off offset:64 sc0 sc1\n\t"
    "global_load_dwordx4 %10, %17, off offset:128 sc0 sc1\n\t"
    "global_load_dwordx4 %11, %17, off offset:192 sc0 sc1\n\t"
    "global_load_dwordx4 %12, %17, off offset:256 sc0 sc1\n\t"
    "global_load_dwordx4 %13, %17, off offset:320 sc0 sc1\n\t"
    "global_load_dwordx4 %14, %17, off offset:384 sc0 sc1\n\t"
    "global_load_dwordx4 %15, %17, off offset:448 sc0 sc1\n\t"
    "s_waitcnt vmcnt(0)"
    : "=&v"(a[0]),"=&v"(a[1]),"=&v"(a[2]),"=&v"(a[3]),
      "=&v"(a[4]),"=&v"(a[5]),"=&v"(a[6]),"=&v"(a[7]),
      "=&v"(b[0]),"=&v"(b[1]),"=&v"(b[2]),"=&v"(b[3]),
      "=&v"(b[4]),"=&v"(b[5]),"=&v"(b[6]),"=&v"(b[7])
    : "v"(p0), "v"(p1) : "memory");
}

// ---- gate tables: T[v][h] = sum_e emb[v,e]*w[e,h] + b[h], v in 0..2 ----
__global__ void k_tables(const float* __restrict__ emb, const float* __restrict__ w,
                         const float* __restrict__ bias, float* __restrict__ T){
  int h = blockIdx.x*256 + threadIdx.x;
  float a0=0.f, a1=0.f, a2=0.f;
  for(int e=0;e<512;e++){
    float we = w[e*1024 + h];
    a0 += emb[e]*we; a1 += emb[512+e]*we; a2 += emb[1024+e]*we;
  }
  float b = bias[h];
  T[h] = a0+b; T[1024+h] = a1+b; T[2048+h] = a2+b;
}

// ---- transpose 1024x1024 f32 -> f16 wT[n][k] = w[k][n] ----
__global__ void k_transpose(const float* __restrict__ w, unsigned short* __restrict__ wT){
  __shared__ float tile[64][65];
  int tr = blockIdx.x & 15, tc = blockIdx.x >> 4;
  int col = threadIdx.x & 63;
  int r0  = threadIdx.x >> 6;
  for(int rr=0; rr<16; rr++){
    int row = rr*4 + r0;
    tile[row][col] = w[(tr*64+row)*1024 + tc*64 + col];
  }
  __syncthreads();
  for(int rr=0; rr<16; rr++){
    int row = rr*4 + r0;
    wT[(tc*64+row)*1024 + tr*64 + col] = f2h(tile[col][row]);
  }
}

// update + publish for one group (r5-verbatim math)
__device__ __forceinline__ void upd_pub(const float* xb, const float (&tT)[3][3][2],
    int v, int b_l, int h_l, float& cm0, float& cm1,
    unsigned short* wrp, int bg, int nbase){
  int r16 = b_l & 15, mh = b_l >> 4, reg = r16 & 3, lq = r16 >> 2;
  float cn[2];
  #pragma unroll
  for(int j=0;j<2;j++){
    int col = h_l + j, nh = col >> 4, l = (lq<<4) | (col & 15);
    float mi = 0.f, mf = 0.f;
    #pragma unroll
    for(int q=0;q<4;q++){
      const float* base = xb + ((q*2+mh)*4 + nh)*256 + l*4 + reg;
      mi += base[0];
      mf += base[512];
    }
    float ti = (v==0)?tT[0][0][j]:(v==1)?tT[0][1][j]:tT[0][2][j];
    float tf = (v==0)?tT[1][0][j]:(v==1)?tT[1][1][j]:tT[1][2][j];
    float tc = (v==0)?tT[2][0][j]:(v==1)?tT[2][1][j]:tT[2][2][j];
    float cm = j ? cm1 : cm0;
    cn[j] = sigf(tc)*sigf(ti + mi) + cm*sigf(tf + mf);
  }
  cm0 = cn[0]; cm1 = cn[1];
  unsigned pk = (unsigned)f2h(cn[0]) | (((unsigned)f2h(cn[1]))<<16);
  st32_coh_nw(reinterpret_cast<unsigned*>(wrp + bg*1024 + nbase + h_l), pk);
}

// final-step update: h = tanh(c)*sigmoid(o)*pad -> hbuf
__device__ __forceinline__ void upd_last(const float* xb, const float* xo,
    const float (&tT)[3][3][2], const float* To, int v, int b_l, int h_l,
    float cm0, float cm1, float* hbuf, int bg, int nbase){
  int r16 = b_l & 15, mh = b_l >> 4, reg = r16 & 3, lq = r16 >> 2;
  float hh[2];
  #pragma unroll
  for(int j=0;j<2;j++){
    int col = h_l + j, nh = col >> 4, l = (lq<<4) | (col & 15);
    float mi = 0.f, mf = 0.f, mo = 0.f;
    #pragma unroll
    for(int q=0;q<4;q++){
      const float* base = xb + ((q*2+mh)*4 + nh)*256 + l*4 + reg;
      mi += base[0];
      mf += base[512];
      mo += xo[((q*2+mh)*2 + nh)*256 + l*4 + reg];
    }
    float ti = (v==0)?tT[0][0][j]:(v==1)?tT[0][1][j]:tT[0][2][j];
    float tf = (v==0)?tT[1][0][j]:(v==1)?tT[1][1][j]:tT[1][2][j];
    float tc = (v==0)?tT[2][0][j]:(v==1)?tT[2][1][j]:tT[2][2][j];
    float cm = j ? cm1 : cm0;
    float c2 = sigf(tc)*sigf(ti + mi) + cm*sigf(tf + mf);
    float to = To[v*1024 + nbase + col];
    float pad = (float)((v+1)>>1);
    hh[j] = tanhf(c2)*sigf(to + mo)*pad;
  }
  *reinterpret_cast<float2*>(hbuf + bg*1024 + nbase + h_l) = make_float2(hh[0], hh[1]);
}

// ---- sequential recurrence: 128 WGs; each hosts col-slice ng for TWO groups
// (pid, pid+4). Per round: 1 poll + 1 combined A-load + 2 compute phases +
// 1 drain + 1 flag — r5's protocol with all sync costs amortized over 2 steps.
__global__ void __launch_bounds__(512,1) k_recur(
    const int* __restrict__ x,
    const unsigned short* __restrict__ wTi,   // w_ih^T f16 [n][k]
    const unsigned short* __restrict__ wTf,
    const unsigned short* __restrict__ wTo,
    const float* __restrict__ Ti, const float* __restrict__ Tf,
    const float* __restrict__ To, const float* __restrict__ Tc,
    unsigned short* __restrict__ cbf,         // [2][256][1024] f16 planes
    float* __restrict__ hbuf,
    unsigned* __restrict__ bars)              // [4 pid][32 ng] combined flags
{
  __shared__ __align__(16) float xch[8192];   // 32KB accumulator exchange
  __shared__ __align__(16) float xo[4096];    // 16KB o-gate (epilogue)

  const int tid  = threadIdx.x;
  const int wid  = tid >> 6;
  const int lane = tid & 63;
  const int pid  = blockIdx.x & 3;
  const int ng   = blockIdx.x >> 2;           // 0..31
  const int mb0  = pid*32;
  const int mb1  = (pid+4)*32;
  const int nbase = ng*32;

  const int mh_w = wid & 1;
  const int q_w  = wid >> 1;

  // ---- B (i,f gates; both 16-col halves; this wave's k-quarter) — shared by both groups ----
  const int bcol0 = nbase + (lane&15);
  const int bcol1 = bcol0 + 16;
  const int bk    = q_w*256 + (lane>>4)*8;
  f16x8 Bi0[8], Bi1[8], Bf0[8], Bf1[8];
  #pragma unroll
  for(int kk=0;kk<8;kk++){
    Bi0[kk] = *reinterpret_cast<const f16x8*>(wTi + bcol0*1024 + bk + kk*32);
    Bi1[kk] = *reinterpret_cast<const f16x8*>(wTi + bcol1*1024 + bk + kk*32);
    Bf0[kk] = *reinterpret_cast<const f16x8*>(wTf + bcol0*1024 + bk + kk*32);
    Bf1[kk] = *reinterpret_cast<const f16x8*>(wTf + bcol1*1024 + bk + kk*32);
  }

  const int b_l = tid >> 4;            // owned batch row 0..31 (per group)
  const int h_l = (tid & 15)*2;        // owned col pair in slice
  const int bg0 = mb0 + b_l;
  const int bg1 = mb1 + b_l;

  float tT[3][3][2];                   // column-dependent only -> shared by groups
  { const float* Tp[3] = {Ti, Tf, Tc};
    #pragma unroll
    for(int g=0; g<3; g++)
      #pragma unroll
      for(int v=0; v<3; v++)
        #pragma unroll
        for(int j=0; j<2; j++) tT[g][v][j] = Tp[g][v*1024 + nbase + h_l + j];
  }
  float cm0a=0.f, cm1a=0.f, cm0b=0.f, cm1b=0.f;   // master c (f32) per group

  const int arow = mh_w*16 + (lane&15);
  const int aoff = q_w*256 + ((lane>>4)<<3);
  const unsigned* pollp = bars + pid*32 + q_w*8 + (lane&7);
  unsigned* flagp = bars + pid*32 + ng;

  for(int t=0; t<NSTEP-1; ++t){
    const unsigned short* rdp = cbf + (unsigned)(t&1)*262144u;
    unsigned short*       wrp = cbf + (unsigned)((t+1)&1)*262144u;

    // ---- one poll covers both groups (flag = WG published both, drained) ----
    if(t > 0){
      const unsigned tgt = (unsigned)t;
      while(true){
        unsigned v = ld32_coh(pollp);
        if(__all((int)(v >= tgt))) break;
        __builtin_amdgcn_s_sleep(1);
      }
    }
    int v0 = ldx(x + bg0*512 + t);
    int v1 = ldx(x + bg1*512 + t);

    // ---- combined A-load: both groups through one L3 round-trip window ----
    f16x8 a0[8], a1[8];
    ldA16_coh2(rdp + (mb0+arow)*1024 + aoff, rdp + (mb1+arow)*1024 + aoff, a0, a1);

    // ---- group 0: MFMA -> xch -> update+publish ----
    {
      f32x4 c00={0.f,0.f,0.f,0.f}, c01={0.f,0.f,0.f,0.f};
      f32x4 c10={0.f,0.f,0.f,0.f}, c11={0.f,0.f,0.f,0.f};
      #pragma unroll
      for(int kk=0;kk<8;kk++){
        c00 = __builtin_amdgcn_mfma_f32_16x16x32_f16(a0[kk], Bi0[kk], c00, 0,0,0);
        c01 = __builtin_amdgcn_mfma_f32_16x16x32_f16(a0[kk], Bi1[kk], c01, 0,0,0);
        c10 = __builtin_amdgcn_mfma_f32_16x16x32_f16(a0[kk], Bf0[kk], c10, 0,0,0);
        c11 = __builtin_amdgcn_mfma_f32_16x16x32_f16(a0[kk], Bf1[kk], c11, 0,0,0);
      }
      *reinterpret_cast<f32x4*>(xch + (wid*4 + 0)*256 + lane*4) = c00;
      *reinterpret_cast<f32x4*>(xch + (wid*4 + 1)*256 + lane*4) = c01;
      *reinterpret_cast<f32x4*>(xch + (wid*4 + 2)*256 + lane*4) = c10;
      *reinterpret_cast<f32x4*>(xch + (wid*4 + 3)*256 + lane*4) = c11;
    }
    __syncthreads();                   // B1: g0 xch ready
    upd_pub(xch, tT, v0, b_l, h_l, cm0a, cm1a, wrp, bg0, nbase);

    // ---- group 1: MFMA (regs only, fills B2 wait) -> xch -> update+publish ----
    f32x4 d00={0.f,0.f,0.f,0.f}, d01={0.f,0.f,0.f,0.f};
    f32x4 d10={0.f,0.f,0.f,0.f}, d11={0.f,0.f,0.f,0.f};
    #pragma unroll
    for(int kk=0;kk<8;kk++){
      d00 = __builtin_amdgcn_mfma_f32_16x16x32_f16(a1[kk], Bi0[kk], d00, 0,0,0);
      d01 = __builtin_amdgcn_mfma_f32_16x16x32_f16(a1[kk], Bi1[kk], d01, 0,0,0);
      d10 = __builtin_amdgcn_mfma_f32_16x16x32_f16(a1[kk], Bf0[kk], d10, 0,0,0);
      d11 = __builtin_amdgcn_mfma_f32_16x16x32_f16(a1[kk], Bf1[kk], d11, 0,0,0);
    }
    __syncthreads();                   // B2: everyone done reading g0 xch
    *reinterpret_cast<f32x4*>(xch + (wid*4 + 0)*256 + lane*4) = d00;
    *reinterpret_cast<f32x4*>(xch + (wid*4 + 1)*256 + lane*4) = d01;
    *reinterpret_cast<f32x4*>(xch + (wid*4 + 2)*256 + lane*4) = d10;
    *reinterpret_cast<f32x4*>(xch + (wid*4 + 3)*256 + lane*4) = d11;
    __syncthreads();                   // B3: g1 xch ready
    upd_pub(xch, tT, v1, b_l, h_l, cm0b, cm1b, wrp, bg1, nbase);

    // ---- round close: drain both publishes, post combined flag ----
    asm volatile("s_waitcnt vmcnt(0)" ::: "memory");
    __syncthreads();                   // B4: all threads drained
    if(tid == 0) st32_coh_nw(flagp, (unsigned)(t+1));
  }

  // ================= epilogue: t = NSTEP-1 (adds o-gate, writes h) =========
  {
    const int t = NSTEP-1;
    const unsigned short* rdp = cbf + (unsigned)(t&1)*262144u;
    const unsigned tgt = (unsigned)t;
    while(true){
      unsigned v = ld32_coh(pollp);
      if(__all((int)(v >= tgt))) break;
      __builtin_amdgcn_s_sleep(1);
    }
    int v0 = ldx(x + bg0*512 + t);
    int v1 = ldx(x + bg1*512 + t);
    f16x8 a0[8], a1[8];
    ldA16_coh2(rdp + (mb0+arow)*1024 + aoff, rdp + (mb1+arow)*1024 + aoff, a0, a1);

    // group 0
    {
      f32x4 c00={0.f,0.f,0.f,0.f}, c01={0.f,0.f,0.f,0.f};
      f32x4 c10={0.f,0.f,0.f,0.f}, c11={0.f,0.f,0.f,0.f};
      f32x4 o0={0.f,0.f,0.f,0.f},  o1={0.f,0.f,0.f,0.f};
      #pragma unroll
      for(int kk=0;kk<8;kk++){
        f16x8 bo0 = *reinterpret_cast<const f16x8*>(wTo + bcol0*1024 + bk + kk*32);
        f16x8 bo1 = *reinterpret_cast<const f16x8*>(wTo + bcol1*1024 + bk + kk*32);
        c00 = __builtin_amdgcn_mfma_f32_16x16x32_f16(a0[kk], Bi0[kk], c00, 0,0,0);
        c01 = __builtin_amdgcn_mfma_f32_16x16x32_f16(a0[kk], Bi1[kk], c01, 0,0,0);
        c10 = __builtin_amdgcn_mfma_f32_16x16x32_f16(a0[kk], Bf0[kk], c10, 0,0,0);
        c11 = __builtin_amdgcn_mfma_f32_16x16x32_f16(a0[kk], Bf1[kk], c11, 0,0,0);
        o0  = __builtin_amdgcn_mfma_f32_16x16x32_f16(a0[kk], bo0,     o0,  0,0,0);
        o1  = __builtin_amdgcn_mfma_f32_16x16x32_f16(a0[kk], bo1,     o1,  0,0,0);
      }
      *reinterpret_cast<f32x4*>(xch + (wid*4 + 0)*256 + lane*4) = c00;
      *reinterpret_cast<f32x4*>(xch + (wid*4 + 1)*256 + lane*4) = c01;
      *reinterpret_cast<f32x4*>(xch + (wid*4 + 2)*256 + lane*4) = c10;
      *reinterpret_cast<f32x4*>(xch + (wid*4 + 3)*256 + lane*4) = c11;
      *reinterpret_cast<f32x4*>(xo  + (wid*2 + 0)*256 + lane*4) = o0;
      *reinterpret_cast<f32x4*>(xo  + (wid*2 + 1)*256 + lane*4) = o1;
    }
    __syncthreads();
    upd_last(xch, xo, tT, To, v0, b_l, h_l, cm0a, cm1a, hbuf, bg0, nbase);

    // group 1
    {
      f32x4 c00={0.f,0.f,0.f,0.f}, c01={0.f,0.f,0.f,0.f};
      f32x4 c10={0.f,0.f,0.f,0.f}, c11={0.f,0.f,0.f,0.f};
      f32x4 o0={0.f,0.f,0.f,0.f},  o1={0.f,0.f,0.f,0.f};
      #pragma unroll
      for(int kk=0;kk<8;kk++){
        f16x8 bo0 = *reinterpret_cast<const f16x8*>(wTo + bcol0*1024 + bk + kk*32);
        f16x8 bo1 = *reinterpret_cast<const f16x8*>(wTo + bcol1*1024 + bk + kk*32);
        c00 = __builtin_amdgcn_mfma_f32_16x16x32_f16(a1[kk], Bi0[kk], c00, 0,0,0);
        c01 = __builtin_amdgcn_mfma_f32_16x16x32_f16(a1[kk], Bi1[kk], c01, 0,0,0);
        c10 = __builtin_amdgcn_mfma_f32_16x16x32_f16(a1[kk], Bf0[kk], c10, 0,0,0);
        c11 = __builtin_amdgcn_mfma_f32_16x16x32_f16(a1[kk], Bf1[kk], c11, 0,0,0);
        o0  = __builtin_amdgcn_mfma_f32_16x16x32_f16(a1[kk], bo0,     o0,  0,0,0);
        o1  = __builtin_amdgcn_mfma_f32_16x16x32_f16(a1[kk], bo1,     o1,  0,0,0);
      }
      __syncthreads();                 // everyone done reading g0's xch/xo
      *reinterpret_cast<f32x4*>(xch + (wid*4 + 0)*256 + lane*4) = c00;
      *reinterpret_cast<f32x4*>(xch + (wid*4 + 1)*256 + lane*4) = c01;
      *reinterpret_cast<f32x4*>(xch + (wid*4 + 2)*256 + lane*4) = c10;
      *reinterpret_cast<f32x4*>(xch + (wid*4 + 3)*256 + lane*4) = c11;
      *reinterpret_cast<f32x4*>(xo  + (wid*2 + 0)*256 + lane*4) = o0;
      *reinterpret_cast<f32x4*>(xo  + (wid*2 + 1)*256 + lane*4) = o1;
    }
    __syncthreads();
    upd_last(xch, xo, tT, To, v1, b_l, h_l, cm0b, cm1b, hbuf, bg1, nbase);
  }
}

// ---- projection + log_softmax over axis 0 (batch) ----
__global__ void k_proj(const float* __restrict__ hbuf, const float* __restrict__ w_ph,
                       const float* __restrict__ b_p, float* __restrict__ out){
  const int c = blockIdx.x;    // 0..9
  const int b = threadIdx.x;   // 0..255
  float acc = b_p[c];
  const float4* hb = reinterpret_cast<const float4*>(hbuf + b*1024);
  for(int i=0;i<256;i++){
    float4 hv = hb[i];
    int h = i*4;
    acc += hv.x*w_ph[h*10+c] + hv.y*w_ph[(h+1)*10+c] + hv.z*w_ph[(h+2)*10+c] + hv.w*w_ph[(h+3)*10+c];
  }
  __shared__ float red[256];
  red[b] = acc; __syncthreads();
  for(int s=128;s>0;s>>=1){ if(b<s) red[b]=fmaxf(red[b],red[b+s]); __syncthreads(); }
  float m = red[0]; __syncthreads();
  red[b] = expf(acc-m); __syncthreads();
  for(int s=128;s>0;s>>=1){ if(b<s) red[b]+=red[b+s]; __syncthreads(); }
  out[b*10+c] = acc - m - logf(red[0]);
}

extern "C" void kernel_launch(void* const* d_in, const int* in_sizes, int n_in,
                              void* d_out, int out_size, void* d_ws, size_t ws_size,
                              hipStream_t stream){
  const int*   x    = (const int*)  d_in[0];
  const float* emb  = (const float*)d_in[1];
  const float* w_cx = (const float*)d_in[2];
  const float* b_c  = (const float*)d_in[3];
  const float* w_ix = (const float*)d_in[4];
  const float* w_ih = (const float*)d_in[5];
  const float* b_i  = (const float*)d_in[6];
  const float* w_fx = (const float*)d_in[7];
  const float* w_fh = (const float*)d_in[8];
  const float* b_f  = (const float*)d_in[9];
  const float* w_ox = (const float*)d_in[10];
  const float* w_oh = (const float*)d_in[11];
  const float* b_o  = (const float*)d_in[12];
  const float* w_ph = (const float*)d_in[13];
  const float* b_p  = (const float*)d_in[14];
  float* out = (float*)d_out;

  char* ws = (char*)d_ws;
  float* Ti = (float*)(ws);
  float* Tf = (float*)(ws + 12288);
  float* To = (float*)(ws + 24576);
  float* Tc = (float*)(ws + 36864);
  unsigned short* wTi = (unsigned short*)(ws + 49152);
  unsigned short* wTf = (unsigned short*)(ws + 2146304);
  unsigned short* wTo = (unsigned short*)(ws + 4243456);
  unsigned short* cbf = (unsigned short*)(ws + 6340608);  // 2 planes x 512KB f16
  unsigned* bars = (unsigned*)(ws + 7389184);             // 4 pid x 32 ng flags
  float* hbuf = (float*)(ws + 7391232);                   // 1MB

  hipMemsetAsync(cbf, 0, 1048576 + 2048, stream);   // c planes + flags
  k_tables<<<4,256,0,stream>>>(emb, w_ix, b_i, Ti);
  k_tables<<<4,256,0,stream>>>(emb, w_fx, b_f, Tf);
  k_tables<<<4,256,0,stream>>>(emb, w_ox, b_o, To);
  k_tables<<<4,256,0,stream>>>(emb, w_cx, b_c, Tc);
  k_transpose<<<256,256,0,stream>>>(w_ih, wTi);
  k_transpose<<<256,256,0,stream>>>(w_fh, wTf);
  k_transpose<<<256,256,0,stream>>>(w_oh, wTo);

  void* args[] = { (void*)&x, (void*)&wTi, (void*)&wTf, (void*)&wTo,
                   (void*)&Ti, (void*)&Tf, (void*)&To, (void*)&Tc,
                   (void*)&cbf, (void*)&hbuf, (void*)&bars };
  (void)hipLaunchCooperativeKernel((void*)k_recur, dim3(128), dim3(512), args, 0, stream);
  k_proj<<<10,256,0,stream>>>(hbuf, w_ph, b_p, out);
}

// Round 14
// 2329.357 us; speedup vs baseline: 2.7136x; 1.7494x over previous
//
#include <hip/hip_runtime.h>
#include <hip/hip_bf16.h>
#include <hip/hip_fp16.h>

typedef __attribute__((ext_vector_type(8))) _Float16 f16x8;
typedef __attribute__((ext_vector_type(4))) float f32x4;

#define NSTEP 511

__device__ __forceinline__ unsigned short f2h(float f){ return __half_as_ushort(__float2half(f)); }
__device__ __forceinline__ float sigf(float z){ return 1.0f/(1.0f + __expf(-z)); }

// Agent-coherent primitives: sc0 sc1 bypasses L1/L2, served by the memory-side
// L3 (coherent point across XCDs). Store includes inline drain (r5-verbatim).
__device__ __forceinline__ void st32_coh(unsigned* p, unsigned v){
  asm volatile("global_store_dword %0, %1, off sc0 sc1\n\ts_waitcnt vmcnt(0)"
               :: "v"(p), "v"(v) : "memory");
}
__device__ __forceinline__ unsigned ld32_coh(const unsigned* p){
  unsigned v;
  asm volatile("global_load_dword %0, %1, off sc0 sc1\n\ts_waitcnt vmcnt(0)"
               : "=v"(v) : "v"(p) : "memory");
  return v;
}
// 8x16B coherent loads + in-block waitcnt (consumers safe after the block).
__device__ __forceinline__ void ldA8_coh(const void* p, f16x8 a[8]){
  asm volatile(
    "global_load_dwordx4 %0, %8, off sc0 sc1\n\t"
    "global_load_dwordx4 %1, %8, off offset:64 sc0 sc1\n\t"
    "global_load_dwordx4 %2, %8, off offset:128 sc0 sc1\n\t"
    "global_load_dwordx4 %3, %8, off offset:192 sc0 sc1\n\t"
    "global_load_dwordx4 %4, %8, off offset:256 sc0 sc1\n\t"
    "global_load_dwordx4 %5, %8, off offset:320 sc0 sc1\n\t"
    "global_load_dwordx4 %6, %8, off offset:384 sc0 sc1\n\t"
    "global_load_dwordx4 %7, %8, off offset:448 sc0 sc1\n\t"
    "s_waitcnt vmcnt(0)"
    : "=&v"(a[0]),"=&v"(a[1]),"=&v"(a[2]),"=&v"(a[3]),
      "=&v"(a[4]),"=&v"(a[5]),"=&v"(a[6]),"=&v"(a[7])
    : "v"(p) : "memory");
}

// ---- gate tables, all 4 gates in one launch: grid (4 x, 4 y) ----
// T layout per gate: T[v][h], v in 0..2
__global__ void k_tables4(const float* __restrict__ emb,
                          const float* __restrict__ wi, const float* __restrict__ bi,
                          const float* __restrict__ wf, const float* __restrict__ bf,
                          const float* __restrict__ wo, const float* __restrict__ bo,
                          const float* __restrict__ wc, const float* __restrict__ bc,
                          float* __restrict__ Ti, float* __restrict__ Tf,
                          float* __restrict__ To, float* __restrict__ Tc){
  const float* w  = (blockIdx.y==0)?wi:(blockIdx.y==1)?wf:(blockIdx.y==2)?wo:wc;
  const float* bs = (blockIdx.y==0)?bi:(blockIdx.y==1)?bf:(blockIdx.y==2)?bo:bc;
  float*       T  = (blockIdx.y==0)?Ti:(blockIdx.y==1)?Tf:(blockIdx.y==2)?To:Tc;
  int h = blockIdx.x*256 + threadIdx.x;
  float a0=0.f, a1=0.f, a2=0.f;
  for(int e=0;e<512;e++){
    float we = w[e*1024 + h];
    a0 += emb[e]*we; a1 += emb[512+e]*we; a2 += emb[1024+e]*we;
  }
  float b = bs[h];
  T[h] = a0+b; T[1024+h] = a1+b; T[2048+h] = a2+b;
}

// ---- transpose 1024x1024 f32 -> f16, all 3 weights in one launch ----
__global__ void k_transpose3(const float* __restrict__ wi, unsigned short* __restrict__ wTi,
                             const float* __restrict__ wf, unsigned short* __restrict__ wTf,
                             const float* __restrict__ wo, unsigned short* __restrict__ wTo){
  const float* w = (blockIdx.y==0)?wi:(blockIdx.y==1)?wf:wo;
  unsigned short* wT = (blockIdx.y==0)?wTi:(blockIdx.y==1)?wTf:wTo;
  __shared__ float tile[64][65];
  int tr = blockIdx.x & 15, tc = blockIdx.x >> 4;
  int col = threadIdx.x & 63;
  int r0  = threadIdx.x >> 6;
  for(int rr=0; rr<16; rr++){
    int row = rr*4 + r0;
    tile[row][col] = w[(tr*64+row)*1024 + tc*64 + col];
  }
  __syncthreads();
  for(int rr=0; rr<16; rr++){
    int row = rr*4 + r0;
    wT[(tc*64+row)*1024 + tr*64 + col] = f2h(tile[col][row]);
  }
}

// ---- sequential recurrence: 256 WGs = 8 batch-groups x 32 col-slices ----
// PROVEN round-5 protocol (2.42 ms, best of 9 structural variants):
// per-wave poll of the 8 producer WG flags -> A-load -> 32 MFMA -> xch ->
// barrier -> update -> publish(inline drain) -> barrier -> tid0 flag.
// All cross-WG data via sc0sc1 (memory-side L3 = coherent point): placement-
// independent, no cache maintenance, two-barrier lockstep keeps the convoy
// phase-locked (every de-sync variant measured slower).
__global__ void __launch_bounds__(512,1) k_recur(
    const int* __restrict__ x,
    const unsigned short* __restrict__ wTi,   // w_ih^T f16 [n][k]
    const unsigned short* __restrict__ wTf,
    const unsigned short* __restrict__ wTo,
    const float* __restrict__ Ti, const float* __restrict__ Tf,
    const float* __restrict__ To, const float* __restrict__ Tc,
    unsigned short* __restrict__ cbf,         // [2][256][1024] f16 planes
    float* __restrict__ hbuf,
    unsigned int* __restrict__ bars)          // [8 grp][64] flags
{
  __shared__ __align__(16) float xch[8192];   // 32KB accumulator exchange
  __shared__ __align__(16) float xo[4096];    // 16KB o-gate (last step)

  const int tid  = threadIdx.x;
  const int wid  = tid >> 6;
  const int lane = tid & 63;
  const int mg   = blockIdx.x & 7;
  const int ng   = blockIdx.x >> 3;
  const int mbase = mg*32;
  const int nbase = ng*32;

  const int mh_w = wid & 1;
  const int q_w  = wid >> 1;

  // ---- B (i,f gates; both 16-col halves; this wave's k-quarter) into VGPRs ----
  const int bcol0 = nbase + (lane&15);
  const int bcol1 = bcol0 + 16;
  const int bk    = q_w*256 + (lane>>4)*8;
  f16x8 Bi0[8], Bi1[8], Bf0[8], Bf1[8];
  #pragma unroll
  for(int kk=0;kk<8;kk++){
    Bi0[kk] = *reinterpret_cast<const f16x8*>(wTi + bcol0*1024 + bk + kk*32);
    Bi1[kk] = *reinterpret_cast<const f16x8*>(wTi + bcol1*1024 + bk + kk*32);
    Bf0[kk] = *reinterpret_cast<const f16x8*>(wTf + bcol0*1024 + bk + kk*32);
    Bf1[kk] = *reinterpret_cast<const f16x8*>(wTf + bcol1*1024 + bk + kk*32);
  }

  const int b_l = tid >> 4;            // owned batch row 0..31
  const int h_l = (tid & 15)*2;        // owned col pair in slice
  const int bg  = mbase + b_l;

  float tT[3][3][2];
  { const float* Tp[3] = {Ti, Tf, Tc};
    #pragma unroll
    for(int g=0; g<3; g++)
      #pragma unroll
      for(int v=0; v<3; v++)
        #pragma unroll
        for(int j=0; j<2; j++) tT[g][v][j] = Tp[g][v*1024 + nbase + h_l + j];
  }
  float cm0 = 0.f, cm1 = 0.f;          // master c in f32

  const int arow = mh_w*16 + (lane&15);          // row within group
  const int aoff = q_w*256 + ((lane>>4)<<3);     // element offset within row
  unsigned int* arr = bars + mg*64;

  int vc = x[bg*512];

  for(int t=0; t<NSTEP; t++){
    const bool last = (t == NSTEP-1);
    const unsigned short* rdp = cbf + (unsigned)(t&1)*262144u;
    unsigned short*       wrp = cbf + (unsigned)((t+1)&1)*262144u;

    // next-step x value: independent load, hoisted off the critical chain
    int vn = last ? 0 : x[bg*512 + t + 1];

    // ---- per-wave poll: the 8 producers of this wave's k-quarter ----
    if(t > 0){
      const unsigned tgt = (unsigned)t;
      const unsigned* slot = arr + q_w*8 + (lane&7);
      while(true){
        unsigned v = ld32_coh(slot);
        if(__all((int)(v >= tgt))) break;
        __builtin_amdgcn_s_sleep(1);
      }
    }

    // ---- A fragments straight from the coherent plane (no LDS staging) ----
    f16x8 ah[8];
    ldA8_coh(rdp + (mbase + arow)*1024 + aoff, ah);

    // ---- 32 MFMA: i,f gates x 2 col-halves x 8 k-slices ----
    f32x4 a00={0.f,0.f,0.f,0.f}, a01={0.f,0.f,0.f,0.f};
    f32x4 a10={0.f,0.f,0.f,0.f}, a11={0.f,0.f,0.f,0.f};
    #pragma unroll
    for(int kk=0;kk<8;kk++){
      a00 = __builtin_amdgcn_mfma_f32_16x16x32_f16(ah[kk], Bi0[kk], a00, 0,0,0);
      a01 = __builtin_amdgcn_mfma_f32_16x16x32_f16(ah[kk], Bi1[kk], a01, 0,0,0);
      a10 = __builtin_amdgcn_mfma_f32_16x16x32_f16(ah[kk], Bf0[kk], a10, 0,0,0);
      a11 = __builtin_amdgcn_mfma_f32_16x16x32_f16(ah[kk], Bf1[kk], a11, 0,0,0);
    }
    *reinterpret_cast<f32x4*>(xch + (wid*4 + 0)*256 + lane*4) = a00;
    *reinterpret_cast<f32x4*>(xch + (wid*4 + 1)*256 + lane*4) = a01;
    *reinterpret_cast<f32x4*>(xch + (wid*4 + 2)*256 + lane*4) = a10;
    *reinterpret_cast<f32x4*>(xch + (wid*4 + 3)*256 + lane*4) = a11;
    if(last){
      f32x4 o0={0.f,0.f,0.f,0.f}, o1={0.f,0.f,0.f,0.f};
      #pragma unroll
      for(int kk=0;kk<8;kk++){
        f16x8 bo0 = *reinterpret_cast<const f16x8*>(wTo + bcol0*1024 + bk + kk*32);
        f16x8 bo1 = *reinterpret_cast<const f16x8*>(wTo + bcol1*1024 + bk + kk*32);
        o0 = __builtin_amdgcn_mfma_f32_16x16x32_f16(ah[kk], bo0, o0, 0,0,0);
        o1 = __builtin_amdgcn_mfma_f32_16x16x32_f16(ah[kk], bo1, o1, 0,0,0);
      }
      *reinterpret_cast<f32x4*>(xo + (wid*2 + 0)*256 + lane*4) = o0;
      *reinterpret_cast<f32x4*>(xo + (wid*2 + 1)*256 + lane*4) = o1;
    }
    __syncthreads();

    // ---- elementwise update: each thread owns 2 c elements ----
    {
      const int v = vc;
      int r16 = b_l & 15;
      int mh  = b_l >> 4;
      int reg = r16 & 3;
      int lq  = r16 >> 2;
      float cn[2], hh[2];
      #pragma unroll
      for(int j=0;j<2;j++){
        int col = h_l + j;
        int nh  = col >> 4;
        int l   = (lq<<4) | (col & 15);
        float mi = 0.f, mf = 0.f;
        #pragma unroll
        for(int q=0;q<4;q++){
          const float* base = xch + ((q*2+mh)*4 + nh)*256 + l*4 + reg;
          mi += base[0];
          mf += base[512];
        }
        float ti = (v==0)?tT[0][0][j]:(v==1)?tT[0][1][j]:tT[0][2][j];
        float tf = (v==0)?tT[1][0][j]:(v==1)?tT[1][1][j]:tT[1][2][j];
        float tc = (v==0)?tT[2][0][j]:(v==1)?tT[2][1][j]:tT[2][2][j];
        float iv = sigf(ti + mi);
        float fv = sigf(tf + mf);
        float cv = sigf(tc);
        float cm = j ? cm1 : cm0;
        float c2 = cv*iv + cm*fv;
        cn[j] = c2;
        if(last){
          float mo = 0.f;
          #pragma unroll
          for(int q=0;q<4;q++) mo += xo[((q*2+mh)*2 + nh)*256 + l*4 + reg];
          float to = To[v*1024 + nbase + col];
          float ov = sigf(to + mo);
          float pad = (float)((v+1)>>1);
          hh[j] = tanhf(c2)*ov*pad;
        }
      }
      if(!last){
        cm0 = cn[0]; cm1 = cn[1];
        unsigned pk = (unsigned)f2h(cn[0]) | (((unsigned)f2h(cn[1]))<<16);
        st32_coh(reinterpret_cast<unsigned*>(wrp + bg*1024 + nbase + h_l), pk);
      } else {
        *reinterpret_cast<float2*>(hbuf + bg*1024 + nbase + h_l) = make_float2(hh[0], hh[1]);
      }
    }

    if(!last){
      __syncthreads();   // every thread drained its coherent publish (in-asm waitcnt)
      if(tid == 0) st32_coh(&arr[ng], (unsigned)(t+1));
    }
    vc = vn;
  }
}

// ---- projection + log_softmax over axis 0 (batch) ----
__global__ void k_proj(const float* __restrict__ hbuf, const float* __restrict__ w_ph,
                       const float* __restrict__ b_p, float* __restrict__ out){
  const int c = blockIdx.x;    // 0..9
  const int b = threadIdx.x;   // 0..255
  float acc = b_p[c];
  const float4* hb = reinterpret_cast<const float4*>(hbuf + b*1024);
  for(int i=0;i<256;i++){
    float4 hv = hb[i];
    int h = i*4;
    acc += hv.x*w_ph[h*10+c] + hv.y*w_ph[(h+1)*10+c] + hv.z*w_ph[(h+2)*10+c] + hv.w*w_ph[(h+3)*10+c];
  }
  __shared__ float red[256];
  red[b] = acc; __syncthreads();
  for(int s=128;s>0;s>>=1){ if(b<s) red[b]=fmaxf(red[b],red[b+s]); __syncthreads(); }
  float m = red[0]; __syncthreads();
  red[b] = expf(acc-m); __syncthreads();
  for(int s=128;s>0;s>>=1){ if(b<s) red[b]+=red[b+s]; __syncthreads(); }
  out[b*10+c] = acc - m - logf(red[0]);
}

extern "C" void kernel_launch(void* const* d_in, const int* in_sizes, int n_in,
                              void* d_out, int out_size, void* d_ws, size_t ws_size,
                              hipStream_t stream){
  const int*   x    = (const int*)  d_in[0];
  const float* emb  = (const float*)d_in[1];
  const float* w_cx = (const float*)d_in[2];
  const float* b_c  = (const float*)d_in[3];
  const float* w_ix = (const float*)d_in[4];
  const float* w_ih = (const float*)d_in[5];
  const float* b_i  = (const float*)d_in[6];
  const float* w_fx = (const float*)d_in[7];
  const float* w_fh = (const float*)d_in[8];
  const float* b_f  = (const float*)d_in[9];
  const float* w_ox = (const float*)d_in[10];
  const float* w_oh = (const float*)d_in[11];
  const float* b_o  = (const float*)d_in[12];
  const float* w_ph = (const float*)d_in[13];
  const float* b_p  = (const float*)d_in[14];
  float* out = (float*)d_out;

  char* ws = (char*)d_ws;
  float* Ti = (float*)(ws);
  float* Tf = (float*)(ws + 12288);
  float* To = (float*)(ws + 24576);
  float* Tc = (float*)(ws + 36864);
  unsigned short* wTi = (unsigned short*)(ws + 49152);
  unsigned short* wTf = (unsigned short*)(ws + 2146304);
  unsigned short* wTo = (unsigned short*)(ws + 4243456);
  unsigned short* cbf = (unsigned short*)(ws + 6340608);  // 2 planes x 512KB f16
  unsigned int*  bars = (unsigned int*) (ws + 7389184);   // 8 grp x 64 dword flags
  float* hbuf = (float*)(ws + 7391232);                   // 1MB

  hipMemsetAsync(cbf, 0, 1048576 + 2048, stream);   // c planes + flags
  k_tables4<<<dim3(4,4),256,0,stream>>>(emb, w_ix,b_i, w_fx,b_f, w_ox,b_o, w_cx,b_c,
                                        Ti, Tf, To, Tc);
  k_transpose3<<<dim3(256,3),256,0,stream>>>(w_ih, wTi, w_fh, wTf, w_oh, wTo);

  void* args[] = { (void*)&x, (void*)&wTi, (void*)&wTf, (void*)&wTo,
                   (void*)&Ti, (void*)&Tf, (void*)&To, (void*)&Tc,
                   (void*)&cbf, (void*)&hbuf, (void*)&bars };
  (void)hipLaunchCooperativeKernel((void*)k_recur, dim3(256), dim3(512), args, 0, stream);
  k_proj<<<10,256,0,stream>>>(hbuf, w_ph, b_p, out);
}